// Round 1
// baseline (154.851 us; speedup 1.0000x reference)
//
#include <hip/hip_runtime.h>

// Problem constants (B,C,D,H,W) = (2,4,96,160,160)
#define NB 2
#define NC 4
#define ND 96
#define NH 160
#define NW 160

// Tile config: 80 wide x 32 tall output tile, +1 halo each side
constexpr int TW = 80, TH = 32;
constexpr int SW = TW + 2, SH = TH + 2;   // 82 x 34 staged
constexpr int NTW = NW / TW;              // 2
constexpr int NTH = NH / TH;              // 5
constexpr int TILES = NTW * NTH;          // 10 tiles per slice

// loss = S / (B*(D+2)*(H+2)*(W+2)) / C
constexpr float SCALE = 1.0f / (2.0f * 98.0f * 162.0f * 162.0f * 4.0f);

__global__ __launch_bounds__(256) void boundary_loss_kernel(
    const float* __restrict__ pred,   // (B,C,D,H,W) f32
    const int*   __restrict__ target, // (B,D,H,W) i32
    float* __restrict__ out)          // scalar, pre-zeroed
{
    __shared__ float q[NC][SH * SW];  // 4 * 34*82 * 4B = 44.6 KB

    const int tid   = threadIdx.x;
    const int slice = blockIdx.y;          // b*D + d
    const int b     = slice / ND;
    const int d     = slice - b * ND;
    const int tile  = blockIdx.x;
    const int th0   = (tile / NTW) * TH;
    const int tw0   = (tile % NTW) * TW;

    const size_t cstride   = (size_t)ND * NH * NW;                 // class stride
    const size_t sliceBase = ((size_t)b * NC * ND + d) * (NH * NW);
    const size_t tgtBase   = ((size_t)b * ND + d) * (NH * NW);

    // ---- Stage q = softmax(pred) - onehot(target) into LDS (with halo) ----
    for (int idx = tid; idx < SH * SW; idx += 256) {
        const int r  = idx / SW;
        const int cc = idx - r * SW;
        const int gh = th0 + r - 1;
        const int gw = tw0 + cc - 1;
        float q0 = 0.f, q1 = 0.f, q2 = 0.f, q3 = 0.f;
        if (gh >= 0 && gh < NH && gw >= 0 && gw < NW) {
            const size_t off = sliceBase + (size_t)gh * NW + gw;
            const float p0 = pred[off];
            const float p1 = pred[off + cstride];
            const float p2 = pred[off + 2 * cstride];
            const float p3 = pred[off + 3 * cstride];
            const int   t  = target[tgtBase + (size_t)gh * NW + gw];
            const float m  = fmaxf(fmaxf(p0, p1), fmaxf(p2, p3));
            const float e0 = __expf(p0 - m);
            const float e1 = __expf(p1 - m);
            const float e2 = __expf(p2 - m);
            const float e3 = __expf(p3 - m);
            const float inv = 1.0f / (e0 + e1 + e2 + e3);
            q0 = e0 * inv - (t == 0 ? 1.0f : 0.0f);
            q1 = e1 * inv - (t == 1 ? 1.0f : 0.0f);
            q2 = e2 * inv - (t == 2 ? 1.0f : 0.0f);
            q3 = e3 * inv - (t == 3 ? 1.0f : 0.0f);
        }
        q[0][idx] = q0;
        q[1][idx] = q1;
        q[2][idx] = q2;
        q[3][idx] = q3;
    }
    __syncthreads();

    // ---- Sobel (gx^2 + 2*gy^2 since sy == sz) over the tile ----
    float acc = 0.f;
    #pragma unroll
    for (int i = 0; i < (TW * TH) / 256; ++i) {   // 10 pixels/thread
        const int pid = tid + i * 256;
        const int r   = pid / TW + 1;             // staged row
        const int cc  = pid - (r - 1) * TW + 1;   // staged col
        #pragma unroll
        for (int c = 0; c < NC; ++c) {
            const float* s = q[c];
            const float a00 = s[(r - 1) * SW + cc - 1];
            const float a01 = s[(r - 1) * SW + cc];
            const float a02 = s[(r - 1) * SW + cc + 1];
            const float a10 = s[r * SW + cc - 1];
            const float a12 = s[r * SW + cc + 1];
            const float a20 = s[(r + 1) * SW + cc - 1];
            const float a21 = s[(r + 1) * SW + cc];
            const float a22 = s[(r + 1) * SW + cc + 1];
            const float gx = (a02 - a00) + 2.f * (a12 - a10) + (a22 - a20);
            const float gy = (a20 - a00) + 2.f * (a21 - a01) + (a22 - a02);
            acc += gx * gx + 2.f * gy * gy;
        }
    }

    // ---- Block reduction -> one atomic per block ----
    #pragma unroll
    for (int off = 32; off > 0; off >>= 1)
        acc += __shfl_down(acc, off, 64);
    __shared__ float wsum[4];
    if ((tid & 63) == 0) wsum[tid >> 6] = acc;
    __syncthreads();
    if (tid == 0) {
        const float s = wsum[0] + wsum[1] + wsum[2] + wsum[3];
        atomicAdd(out, s * SCALE);
    }
}

extern "C" void kernel_launch(void* const* d_in, const int* in_sizes, int n_in,
                              void* d_out, int out_size, void* d_ws, size_t ws_size,
                              hipStream_t stream) {
    const float* pred   = (const float*)d_in[0];
    const int*   target = (const int*)d_in[1];
    float*       out    = (float*)d_out;

    // d_out is poisoned with 0xAA before every launch — zero the scalar first.
    hipMemsetAsync(out, 0, sizeof(float), stream);

    dim3 grid(TILES, NB * ND);
    boundary_loss_kernel<<<grid, 256, 0, stream>>>(pred, target, out);
}